// Round 1
// baseline (280.126 us; speedup 1.0000x reference)
//
#include <hip/hip_runtime.h>

// 12-tap filters (fp32, matching reference which casts to x.dtype=float32)
static __device__ __constant__ float F_REC_LO[12] = {
  0.11154074335008017f, 0.4946238903983854f, 0.7511339080215775f, 0.3152503517092432f,
  -0.22626469396516913f, -0.12976686756709563f, 0.09750160558707936f, 0.02752286553001629f,
  -0.031582039318031156f, 0.0005538422009938016f, 0.004777257511010651f, -0.00107730108499558f };
static __device__ __constant__ float F_REC_HI[12] = {
  -0.00107730108499558f, -0.004777257511010651f, 0.0005538422009938016f, 0.031582039318031156f,
  0.02752286553001629f, -0.09750160558707936f, -0.12976686756709563f, 0.22626469396516913f,
  0.3152503517092432f, -0.7511339080215775f, 0.4946238903983854f, -0.11154074335008017f };
static __device__ __constant__ float F_DEC_LO[12] = {
  -0.00107730108499558f, 0.004777257511010651f, 0.0005538422009938016f, -0.031582039318031156f,
  0.02752286553001629f, 0.09750160558707936f, -0.12976686756709563f, -0.22626469396516913f,
  0.3152503517092432f, 0.7511339080215775f, 0.4946238903983854f, 0.11154074335008017f };
static __device__ __constant__ float F_DEC_HI[12] = {
  -0.11154074335008017f, 0.4946238903983854f, -0.7511339080215775f, 0.3152503517092432f,
  0.22626469396516913f, -0.12976686756709563f, -0.09750160558707936f, 0.02752286553001629f,
  0.031582039318031156f, 0.0005538422009938016f, -0.004777257511010651f, -0.00107730108499558f };

// Analysis filter bank: one thread per output sample; computes lo and hi together.
// Symmetric padding via index reflection (single reflection is sufficient for all
// level sizes here: padL<=10 < N_min=18).
__global__ void afb_kernel(const float* __restrict__ in, float* __restrict__ lo,
                           float* __restrict__ hi, int N, int outN, int padL) {
  int row = blockIdx.y;
  int n = blockIdx.x * blockDim.x + threadIdx.x;
  if (n >= outN) return;
  const float* xr = in + (size_t)row * N;
  float accL = 0.f, accH = 0.f;
  int base = 2 * n - padL;
#pragma unroll
  for (int k = 0; k < 12; ++k) {
    int j = base + k;
    j = (j < 0) ? (-j - 1) : j;
    j = (j >= N) ? (2 * N - 1 - j) : j;
    float v = xr[j];
    accL += v * F_REC_LO[k];
    accH += v * F_REC_HI[k];
  }
  size_t o = (size_t)row * outN + n;
  lo[o] = accL;
  hi[o] = accH;
}

// Synthesis filter bank (polyphase): each thread computes the (2m, 2m+1) output
// pair, which share the same 6 lo + 6 hi input reads.
// out[2m]   = sum_t lo[m+t]*DEC_LO[2t+1] + hi[m+t]*DEC_HI[2t+1]
// out[2m+1] = sum_t lo[m+t]*DEC_LO[2t]   + hi[m+t]*DEC_HI[2t]
// outN = 2N-10 (even); m+t in [0, N-1] always -> no bounds checks in the loop.
__global__ void sfb_kernel(const float* __restrict__ y, int strideY,
                           const float* __restrict__ hi, int N,
                           float* __restrict__ out, int outN) {
  int row = blockIdx.y;
  int m = blockIdx.x * blockDim.x + threadIdx.x;
  int nPairs = outN >> 1;  // == N - 5
  if (m >= nPairs) return;
  const float* yr = y + (size_t)row * strideY;
  const float* hr = hi + (size_t)row * N;
  float aE = 0.f, aO = 0.f;
#pragma unroll
  for (int t = 0; t < 6; ++t) {
    float lv = yr[m + t];
    float hv = hr[m + t];
    aE += lv * F_DEC_LO[2 * t + 1] + hv * F_DEC_HI[2 * t + 1];
    aO += lv * F_DEC_LO[2 * t]     + hv * F_DEC_HI[2 * t];
  }
  *reinterpret_cast<float2*>(out + (size_t)row * outN + 2 * m) = make_float2(aE, aO);
}

// einsum('bix,iox->box'): in (256,64,14), w (64,64,14), out (256,64,14).
// One block per b; input slice staged in LDS; thread t -> (o = t/14, x = t%14),
// so both weight reads and output writes are fully coalesced.
__global__ void mix_kernel(const float* __restrict__ in, const float* __restrict__ w,
                           float* __restrict__ out) {
  __shared__ float s_in[896];
  int b = blockIdx.x;
  int t = threadIdx.x;  // 896 = 64*14 threads
  s_in[t] = in[(size_t)b * 896 + t];
  __syncthreads();
  int x = t % 14;
  float acc = 0.f;
#pragma unroll 8
  for (int i = 0; i < 64; ++i) {
    acc += s_in[i * 14 + x] * w[i * 896 + t];
  }
  out[(size_t)b * 896 + t] = acc;
}

extern "C" void kernel_launch(void* const* d_in, const int* in_sizes, int n_in,
                              void* d_out, int out_size, void* d_ws, size_t ws_size,
                              hipStream_t stream) {
  (void)in_sizes; (void)n_in; (void)out_size; (void)ws_size;
  const float* x  = (const float*)d_in[0];
  const float* w1 = (const float*)d_in[1];
  const float* w2 = (const float*)d_in[2];
  float* out = (float*)d_out;
  float* ws  = (float*)d_ws;

  const int R = 256 * 64;  // 16384 independent rows
  // Level lengths: input to level j is lens[j], its output is lens[j+1].
  const int lens[9] = {1024, 517, 264, 137, 74, 42, 26, 18, 14};

  // Workspace layout (floats): hi[0..7] (sum of lens[1..8] = 1092 per row), then bufB.
  size_t off = 0;
  float* hi[8];
  for (int j = 0; j < 8; ++j) { hi[j] = ws + off; off += (size_t)R * lens[j + 1]; }
  float* bufB = ws + off;            // R*518 floats
  // bufA and the mixed-hi buffer live inside d_out (final kernel reads only bufB+hi[0],
  // so overwriting d_out at the last step is safe).
  float* bufA = out;                 // needs <= R*517 floats
  float* hm   = out + (size_t)R * 518;  // R*14 floats

  // ---------------- Analysis ----------------
  const float* cur = x;
  for (int j = 0; j < 8; ++j) {
    int N = lens[j], outN = lens[j + 1];
    int p = 2 * (outN - 1) - N + 12;
    int padL = p / 2;
    float* lo = (j & 1) ? bufB : bufA;  // j even -> bufA, j odd -> bufB (L8 lo ends in bufB)
    int bs = (outN >= 256) ? 256 : ((outN + 63) / 64) * 64;
    dim3 g((outN + bs - 1) / bs, R);
    afb_kernel<<<g, bs, 0, stream>>>(cur, lo, hi[j], N, outN, padL);
    cur = lo;
  }

  // ---------------- Channel mix (einsum) ----------------
  mix_kernel<<<256, 896, 0, stream>>>(cur, w1, bufA);    // lo_mixed -> bufA (len 14)
  mix_kernel<<<256, 896, 0, stream>>>(hi[7], w2, hm);    // hi8_mixed -> hm

  // ---------------- Synthesis ----------------
  const float* y = bufA;
  int strideY = 14;
  for (int s = 0; s < 8; ++s) {
    int N = lens[8 - s];          // length actually consumed (handles truncation)
    int outN = 2 * N - 10;
    const float* hsrc = (s == 0) ? hm : hi[7 - s];
    float* dst = (s == 7) ? out : ((s & 1) ? bufA : bufB);
    int nPairs = outN >> 1;
    int bs = (nPairs >= 256) ? 256 : ((nPairs + 63) / 64) * 64;
    dim3 g((nPairs + bs - 1) / bs, R);
    sfb_kernel<<<g, bs, 0, stream>>>(y, strideY, hsrc, N, dst, outN);
    y = dst;
    strideY = outN;
  }
}

// Round 2
// 136.934 us; speedup vs baseline: 2.0457x; 2.0457x over previous
//
#include <hip/hip_runtime.h>

// 12-tap filters (fp32, matching reference which casts to x.dtype=float32)
static __device__ __constant__ float F_REC_LO[12] = {
  0.11154074335008017f, 0.4946238903983854f, 0.7511339080215775f, 0.3152503517092432f,
  -0.22626469396516913f, -0.12976686756709563f, 0.09750160558707936f, 0.02752286553001629f,
  -0.031582039318031156f, 0.0005538422009938016f, 0.004777257511010651f, -0.00107730108499558f };
static __device__ __constant__ float F_REC_HI[12] = {
  -0.00107730108499558f, -0.004777257511010651f, 0.0005538422009938016f, 0.031582039318031156f,
  0.02752286553001629f, -0.09750160558707936f, -0.12976686756709563f, 0.22626469396516913f,
  0.3152503517092432f, -0.7511339080215775f, 0.4946238903983854f, -0.11154074335008017f };
static __device__ __constant__ float F_DEC_LO[12] = {
  -0.00107730108499558f, 0.004777257511010651f, 0.0005538422009938016f, -0.031582039318031156f,
  0.02752286553001629f, 0.09750160558707936f, -0.12976686756709563f, -0.22626469396516913f,
  0.3152503517092432f, 0.7511339080215775f, 0.4946238903983854f, 0.11154074335008017f };
static __device__ __constant__ float F_DEC_HI[12] = {
  -0.11154074335008017f, 0.4946238903983854f, -0.7511339080215775f, 0.3152503517092432f,
  0.22626469396516913f, -0.12976686756709563f, -0.09750160558707936f, 0.02752286553001629f,
  0.031582039318031156f, 0.0005538422009938016f, -0.004777257511010651f, -0.00107730108499558f };

#define NROWS 16384
// lens[j] = length entering analysis level j; lens[j+1] = its output length.
// padL == 10 for every level (verified: p in {20,21} -> p/2 == 10).
// Workspace layout (floats), per-level blocks:
//   hi[j]   at ws + NROWS*HOFF[j], row-major (row, lens[j+1])
//   loFinal at ws + NROWS*1092, (row,14)
//   hm      at ws + NROWS*1106, (row,14)
//   loMixed at ws + NROWS*1120, (row,14)

// ---------------- Fused 8-level analysis: one block per (b,c) row ----------------
__global__ __launch_bounds__(256) void afb_fused(const float* __restrict__ x,
                                                 float* __restrict__ ws) {
  __shared__ float sA[1024];
  __shared__ float sB[520];
  const int lens[9] = {1024, 517, 264, 137, 74, 42, 26, 18, 14};
  const int hoff[8] = {0, 517, 781, 918, 992, 1034, 1060, 1078};
  int row = blockIdx.x;
  int tid = threadIdx.x;

  // Coalesced row load: 256 threads x float4 = 1024 floats.
  reinterpret_cast<float4*>(sA)[tid] =
      reinterpret_cast<const float4*>(x + (size_t)row * 1024)[tid];
  __syncthreads();

  float* cur = sA;
  float* dst = sB;
#pragma unroll
  for (int j = 0; j < 8; ++j) {
    int N = lens[j], outN = lens[j + 1];
    float* hiRow = ws + (size_t)NROWS * hoff[j] + (size_t)row * outN;
    for (int n = tid; n < outN; n += 256) {
      float accL = 0.f, accH = 0.f;
      int base = 2 * n - 10;
#pragma unroll
      for (int k = 0; k < 12; ++k) {
        int jj = base + k;
        jj = (jj < 0) ? (-jj - 1) : jj;
        jj = (jj >= N) ? (2 * N - 1 - jj) : jj;
        float v = cur[jj];
        accL += v * F_REC_LO[k];
        accH += v * F_REC_HI[k];
      }
      dst[n] = accL;
      hiRow[n] = accH;  // coalesced global write
    }
    __syncthreads();
    float* t = cur; cur = dst; dst = t;
  }
  // cur holds final lo (14 floats)
  if (tid < 14) ws[(size_t)NROWS * 1092 + (size_t)row * 14 + tid] = cur[tid];
}

// ---------------- Fused 8-level synthesis: one block per (b,c) row ----------------
// Per step s: y length consumed N (handles the 138->137, 518->517 truncations),
// out length 2N-10. Polyphase: pair (2m,2m+1) shares 6 lo + 6 hi reads.
__global__ __launch_bounds__(256) void sfb_fused(const float* __restrict__ ws,
                                                 float* __restrict__ out) {
  __shared__ float sA[264];
  __shared__ float sB[520];
  __shared__ float sHi[520];
  const int lensY[8] = {14, 18, 26, 42, 74, 137, 264, 517};
  const int hoff[8] = {0, 517, 781, 918, 992, 1034, 1060, 1078};
  int row = blockIdx.x;
  int tid = threadIdx.x;

  if (tid < 14) sA[tid] = ws[(size_t)NROWS * 1120 + (size_t)row * 14 + tid];  // loMixed

  float* cur = sA;
  float* dst = sB;
#pragma unroll
  for (int s = 0; s < 8; ++s) {
    int N = lensY[s];
    const float* hsrc = (s == 0)
        ? (ws + (size_t)NROWS * 1106 + (size_t)row * 14)          // hm (mixed hi8)
        : (ws + (size_t)NROWS * hoff[7 - s] + (size_t)row * N);   // hi[7-s], len == N
    __syncthreads();                       // prev compute done (also covers y0 load)
    for (int n = tid; n < N; n += 256) sHi[n] = hsrc[n];  // coalesced stage
    __syncthreads();
    int nPairs = N - 5;
    if (s < 7) {
      for (int m = tid; m < nPairs; m += 256) {
        float aE = 0.f, aO = 0.f;
#pragma unroll
        for (int t = 0; t < 6; ++t) {
          float lv = cur[m + t], hv = sHi[m + t];
          aE += lv * F_DEC_LO[2 * t + 1] + hv * F_DEC_HI[2 * t + 1];
          aO += lv * F_DEC_LO[2 * t]     + hv * F_DEC_HI[2 * t];
        }
        dst[2 * m] = aE;
        dst[2 * m + 1] = aO;
      }
      float* t = cur; cur = dst; dst = t;
    } else {
      float2* orow = reinterpret_cast<float2*>(out + (size_t)row * 1024);
      for (int m = tid; m < nPairs; m += 256) {
        float aE = 0.f, aO = 0.f;
#pragma unroll
        for (int t = 0; t < 6; ++t) {
          float lv = cur[m + t], hv = sHi[m + t];
          aE += lv * F_DEC_LO[2 * t + 1] + hv * F_DEC_HI[2 * t + 1];
          aO += lv * F_DEC_LO[2 * t]     + hv * F_DEC_HI[2 * t];
        }
        orow[m] = make_float2(aE, aO);  // coalesced 8B stores
      }
    }
  }
}

// einsum('bix,iox->box'): in (256,64,14), w (64,64,14), out (256,64,14).
__global__ void mix_kernel(const float* __restrict__ in, const float* __restrict__ w,
                           float* __restrict__ out) {
  __shared__ float s_in[896];
  int b = blockIdx.x;
  int t = threadIdx.x;  // 896 = 64*14 threads
  s_in[t] = in[(size_t)b * 896 + t];
  __syncthreads();
  int x = t % 14;
  float acc = 0.f;
#pragma unroll 8
  for (int i = 0; i < 64; ++i) {
    acc += s_in[i * 14 + x] * w[i * 896 + t];
  }
  out[(size_t)b * 896 + t] = acc;
}

extern "C" void kernel_launch(void* const* d_in, const int* in_sizes, int n_in,
                              void* d_out, int out_size, void* d_ws, size_t ws_size,
                              hipStream_t stream) {
  (void)in_sizes; (void)n_in; (void)out_size; (void)ws_size;
  const float* x  = (const float*)d_in[0];
  const float* w1 = (const float*)d_in[1];
  const float* w2 = (const float*)d_in[2];
  float* out = (float*)d_out;
  float* ws  = (float*)d_ws;

  // 1) Fused analysis: writes hi[0..7], loFinal.
  afb_fused<<<NROWS, 256, 0, stream>>>(x, ws);

  // 2) Channel mixes at the coarsest level (len 14).
  float* loFinal = ws + (size_t)NROWS * 1092;
  float* hm      = ws + (size_t)NROWS * 1106;
  float* loMixed = ws + (size_t)NROWS * 1120;
  float* hi7     = ws + (size_t)NROWS * 1078;
  mix_kernel<<<256, 896, 0, stream>>>(loFinal, w1, loMixed);
  mix_kernel<<<256, 896, 0, stream>>>(hi7, w2, hm);

  // 3) Fused synthesis: reads loMixed, hm, hi[0..6]; writes d_out.
  sfb_fused<<<NROWS, 256, 0, stream>>>(ws, out);
}

// Round 3
// 84.852 us; speedup vs baseline: 3.3013x; 1.6138x over previous
//
#include <hip/hip_runtime.h>

// Compile-time filter constants (fold to instruction literals).
static constexpr float REC_LO[12] = {
  0.11154074335008017f, 0.4946238903983854f, 0.7511339080215775f, 0.3152503517092432f,
  -0.22626469396516913f, -0.12976686756709563f, 0.09750160558707936f, 0.02752286553001629f,
  -0.031582039318031156f, 0.0005538422009938016f, 0.004777257511010651f, -0.00107730108499558f };
static constexpr float REC_HI[12] = {
  -0.00107730108499558f, -0.004777257511010651f, 0.0005538422009938016f, 0.031582039318031156f,
  0.02752286553001629f, -0.09750160558707936f, -0.12976686756709563f, 0.22626469396516913f,
  0.3152503517092432f, -0.7511339080215775f, 0.4946238903983854f, -0.11154074335008017f };
static constexpr float DEC_LO[12] = {
  -0.00107730108499558f, 0.004777257511010651f, 0.0005538422009938016f, -0.031582039318031156f,
  0.02752286553001629f, 0.09750160558707936f, -0.12976686756709563f, -0.22626469396516913f,
  0.3152503517092432f, 0.7511339080215775f, 0.4946238903983854f, 0.11154074335008017f };
static constexpr float DEC_HI[12] = {
  -0.11154074335008017f, 0.4946238903983854f, -0.7511339080215775f, 0.3152503517092432f,
  0.22626469396516913f, -0.12976686756709563f, -0.09750160558707936f, 0.02752286553001629f,
  0.031582039318031156f, 0.0005538422009938016f, -0.004777257511010651f, -0.00107730108499558f };

#define NROWS 16384
#define WPB 4  // waves (= rows) per block; each wave owns a private LDS slice
// Workspace (floats): hi[j] at NROWS*HOFF[j] (row-major, lens[j+1] per row),
// loFinal @ NROWS*1092, hm @ NROWS*1106, loMixed @ NROWS*1120. Total 74.3 MB.
// Analysis levels: in lens[j] -> out lens[j+1]; padL==10, padR<=11 for all levels.

// ---------------- Fused 8-level analysis: one WAVE per (b,c) row ----------------
__global__ __launch_bounds__(256) void afb_fused(const float* __restrict__ x,
                                                 float* __restrict__ ws) {
  __shared__ float sA[WPB][1048];  // 12-pad + 1024 + 11-pad (origin at 12, 16B-aligned)
  __shared__ float sB[WPB][544];   // 12-pad + 517 + 11-pad
  constexpr int LENS[9] = {1024, 517, 264, 137, 74, 42, 26, 18, 14};
  constexpr int HOFF[8] = {0, 517, 781, 918, 992, 1034, 1060, 1078};
  const int wid = threadIdx.x >> 6;
  const int lane = threadIdx.x & 63;
  const int row = blockIdx.x * WPB + wid;
  float* bufA = sA[wid];
  float* bufB = sB[wid];

  // Coalesced row load: 64 lanes x 4 x float4 = 1024 floats into bufA[12..1035].
  {
    const float4* src = reinterpret_cast<const float4*>(x + (size_t)row * 1024);
    float4* dst4 = reinterpret_cast<float4*>(bufA + 12);
#pragma unroll
    for (int p = 0; p < 4; ++p) dst4[lane + 64 * p] = src[lane + 64 * p];
  }
  // Symmetric pads for level 0 (same-wave ordering via compiler lgkmcnt).
  if (lane < 10) bufA[11 - lane] = bufA[12 + lane];
  if (lane < 11) bufA[12 + 1024 + lane] = bufA[12 + 1023 - lane];

  float* cur = bufA;
  float* dst = bufB;
#pragma unroll
  for (int j = 0; j < 8; ++j) {
    const int N = LENS[j], outN = LENS[j + 1];
    float* hiRow = ws + (size_t)NROWS * HOFF[j] + (size_t)row * outN;
    for (int n = lane; n < outN; n += 64) {
      // taps at padded indices 12 + (2n-10) + k, base even -> 6 aligned float2s
      const float* p = cur + 2 * (n + 1);
      float accL = 0.f, accH = 0.f;
#pragma unroll
      for (int k = 0; k < 6; ++k) {
        float2 v = *reinterpret_cast<const float2*>(p + 2 * k);
        accL += v.x * REC_LO[2 * k] + v.y * REC_LO[2 * k + 1];
        accH += v.x * REC_HI[2 * k] + v.y * REC_HI[2 * k + 1];
      }
      dst[12 + n] = accL;
      hiRow[n] = accH;  // coalesced per-wave global write
    }
    if (j < 7) {  // pads for next level
      if (lane < 10) dst[11 - lane] = dst[12 + lane];
      if (lane < 11) dst[12 + outN + lane] = dst[12 + outN - 1 - lane];
    } else {      // final lo (14)
      if (lane < 14) ws[(size_t)NROWS * 1092 + (size_t)row * 14 + lane] = dst[12 + lane];
    }
    float* t = cur; cur = dst; dst = t;
    (void)N;
  }
}

// ---------------- Fused 8-level synthesis: one WAVE per (b,c) row ----------------
// Per step s: consume N of y (handles 138->137, 518->517 truncation), out 2N-10.
// Pair (2m, 2m+1): out[2m] = sum_t lo[m+t]*DEC_LO[2t+1] + hi[m+t]*DEC_HI[2t+1]
//                  out[2m+1] = sum_t lo[m+t]*DEC_LO[2t] + hi[m+t]*DEC_HI[2t]
__global__ __launch_bounds__(256) void sfb_fused(const float* __restrict__ ws,
                                                 float* __restrict__ out) {
  __shared__ float sA[WPB][268];  // y ping (max 264)
  __shared__ float sB[WPB][520];  // y pong (max 518)
  __shared__ float sH[WPB][520];  // staged hi (max 517)
  constexpr int LENSY[8] = {14, 18, 26, 42, 74, 137, 264, 517};
  constexpr int HOFF[8] = {0, 517, 781, 918, 992, 1034, 1060, 1078};
  const int wid = threadIdx.x >> 6;
  const int lane = threadIdx.x & 63;
  const int row = blockIdx.x * WPB + wid;
  float* bufA = sA[wid];
  float* bufB = sB[wid];
  float* hbuf = sH[wid];

  if (lane < 14) bufA[lane] = ws[(size_t)NROWS * 1120 + (size_t)row * 14 + lane];  // loMixed

  float* cur = bufA;
  float* dst = bufB;
#pragma unroll
  for (int s = 0; s < 8; ++s) {
    const int N = LENSY[s];
    const float* hsrc = (s == 0)
        ? (ws + (size_t)NROWS * 1106 + (size_t)row * 14)              // hm (mixed hi8)
        : (ws + (size_t)NROWS * HOFF[7 - s] + (size_t)row * N);       // hi[7-s], len == N
    for (int n = lane; n < N; n += 64) hbuf[n] = hsrc[n];             // coalesced stage
    const int nP = N - 5;
    if (s < 7) {
      for (int m = lane; m < nP; m += 64) {
        float aE = 0.f, aO = 0.f;
#pragma unroll
        for (int t = 0; t < 6; ++t) {
          float lv = cur[m + t], hv = hbuf[m + t];
          aE += lv * DEC_LO[2 * t + 1] + hv * DEC_HI[2 * t + 1];
          aO += lv * DEC_LO[2 * t]     + hv * DEC_HI[2 * t];
        }
        *reinterpret_cast<float2*>(dst + 2 * m) = make_float2(aE, aO);
      }
      float* t = cur; cur = dst; dst = t;
    } else {
      float2* orow = reinterpret_cast<float2*>(out + (size_t)row * 1024);
      for (int m = lane; m < nP; m += 64) {
        float aE = 0.f, aO = 0.f;
#pragma unroll
        for (int t = 0; t < 6; ++t) {
          float lv = cur[m + t], hv = hbuf[m + t];
          aE += lv * DEC_LO[2 * t + 1] + hv * DEC_HI[2 * t + 1];
          aO += lv * DEC_LO[2 * t]     + hv * DEC_HI[2 * t];
        }
        orow[m] = make_float2(aE, aO);  // coalesced 8B stores
      }
    }
  }
}

// einsum('bix,iox->box'): in (256,64,14), w (64,64,14), out (256,64,14).
// 4 batches per block: each weight load feeds 4 FMAs.
__global__ void mix_kernel(const float* __restrict__ in, const float* __restrict__ w,
                           float* __restrict__ out) {
  __shared__ float s_in[4][896];
  int b0 = blockIdx.x * 4;
  int t = threadIdx.x;  // 896 = 64*14 threads; t -> (o = t/14, x = t%14)
#pragma unroll
  for (int bb = 0; bb < 4; ++bb) s_in[bb][t] = in[(size_t)(b0 + bb) * 896 + t];
  __syncthreads();
  int x = t % 14;
  float acc[4] = {0.f, 0.f, 0.f, 0.f};
#pragma unroll 8
  for (int i = 0; i < 64; ++i) {
    float wv = w[i * 896 + t];
#pragma unroll
    for (int bb = 0; bb < 4; ++bb) acc[bb] += s_in[bb][i * 14 + x] * wv;
  }
#pragma unroll
  for (int bb = 0; bb < 4; ++bb) out[(size_t)(b0 + bb) * 896 + t] = acc[bb];
}

extern "C" void kernel_launch(void* const* d_in, const int* in_sizes, int n_in,
                              void* d_out, int out_size, void* d_ws, size_t ws_size,
                              hipStream_t stream) {
  (void)in_sizes; (void)n_in; (void)out_size; (void)ws_size;
  const float* x  = (const float*)d_in[0];
  const float* w1 = (const float*)d_in[1];
  const float* w2 = (const float*)d_in[2];
  float* out = (float*)d_out;
  float* ws  = (float*)d_ws;

  // 1) Fused analysis: writes hi[0..7], loFinal.
  afb_fused<<<NROWS / WPB, 64 * WPB, 0, stream>>>(x, ws);

  // 2) Channel mixes at the coarsest level (len 14).
  float* loFinal = ws + (size_t)NROWS * 1092;
  float* hm      = ws + (size_t)NROWS * 1106;
  float* loMixed = ws + (size_t)NROWS * 1120;
  float* hi7     = ws + (size_t)NROWS * 1078;
  mix_kernel<<<64, 896, 0, stream>>>(loFinal, w1, loMixed);
  mix_kernel<<<64, 896, 0, stream>>>(hi7, w2, hm);

  // 3) Fused synthesis: reads loMixed, hm, hi[0..6]; writes d_out.
  sfb_fused<<<NROWS / WPB, 64 * WPB, 0, stream>>>(ws, out);
}

// Round 4
// 80.280 us; speedup vs baseline: 3.4893x; 1.0570x over previous
//
#include <hip/hip_runtime.h>

typedef float f2 __attribute__((ext_vector_type(2)));

// Compile-time filter constants (fold to literals).
static constexpr float REC_LO[12] = {
  0.11154074335008017f, 0.4946238903983854f, 0.7511339080215775f, 0.3152503517092432f,
  -0.22626469396516913f, -0.12976686756709563f, 0.09750160558707936f, 0.02752286553001629f,
  -0.031582039318031156f, 0.0005538422009938016f, 0.004777257511010651f, -0.00107730108499558f };
static constexpr float REC_HI[12] = {
  -0.00107730108499558f, -0.004777257511010651f, 0.0005538422009938016f, 0.031582039318031156f,
  0.02752286553001629f, -0.09750160558707936f, -0.12976686756709563f, 0.22626469396516913f,
  0.3152503517092432f, -0.7511339080215775f, 0.4946238903983854f, -0.11154074335008017f };
static constexpr float DEC_LO[12] = {
  -0.00107730108499558f, 0.004777257511010651f, 0.0005538422009938016f, -0.031582039318031156f,
  0.02752286553001629f, 0.09750160558707936f, -0.12976686756709563f, -0.22626469396516913f,
  0.3152503517092432f, 0.7511339080215775f, 0.4946238903983854f, 0.11154074335008017f };
static constexpr float DEC_HI[12] = {
  -0.11154074335008017f, 0.4946238903983854f, -0.7511339080215775f, 0.3152503517092432f,
  0.22626469396516913f, -0.12976686756709563f, -0.09750160558707936f, 0.02752286553001629f,
  0.031582039318031156f, 0.0005538422009938016f, -0.004777257511010651f, -0.00107730108499558f };

#define NROWS 16384
#define WPB 4  // waves (= rows) per block

// ws layout (floats). hi rows padded to x4 so float4 stores/loads are aligned:
//  block      row-stride   block offset (floats/row cumulative * NROWS)
//  hi0        520          0
//  hi1        264          520
//  hi2        140          784
//  hi3        76           924
//  hi4        44           1000
//  hi5        28           1044
//  hi6        20           1072
//  hi7        16           1092
//  loFinal    16           1108
//  hm         16           1124
//  loMixed    16           1140    (end: 1156 floats/row = 75.8 MB)

// ---------------- Fused 8-level analysis: one WAVE per row, 4-wide chunks ----------------
__global__ __launch_bounds__(256) void afb_fused(const float* __restrict__ x,
                                                 float* __restrict__ ws) {
  __shared__ float sA[WPB][1056];  // origin 14; reads up to idx 1055 at level 0
  __shared__ float sB[WPB][548];
  constexpr int LENS[9] = {1024, 517, 264, 137, 74, 42, 26, 18, 14};
  constexpr int HSTR[8] = {520, 264, 140, 76, 44, 28, 20, 16};
  constexpr int HOFF[8] = {0, 520, 784, 924, 1000, 1044, 1072, 1092};
  const int wid = threadIdx.x >> 6;
  const int lane = threadIdx.x & 63;
  const int row = blockIdx.x * WPB + wid;
  float* bufA = sA[wid];
  float* bufB = sB[wid];

  // Coalesced row load into origin-14 buffer (f2 writes: 14+4k is even).
  {
    const float4* src = reinterpret_cast<const float4*>(x + (size_t)row * 1024);
#pragma unroll
    for (int p = 0; p < 4; ++p) {
      float4 v = src[lane + 64 * p];
      int i = 14 + 4 * (lane + 64 * p);
      *reinterpret_cast<f2*>(bufA + i)     = (f2){v.x, v.y};
      *reinterpret_cast<f2*>(bufA + i + 2) = (f2){v.z, v.w};
    }
  }
  if (lane < 10) bufA[13 - lane] = bufA[14 + lane];
  if (lane < 11) bufA[14 + 1024 + lane] = bufA[14 + 1023 - lane];

  float* cur = bufA;
  float* dst = bufB;
#pragma unroll
  for (int j = 0; j < 8; ++j) {
    const int outN = LENS[j + 1];
    const int NCH = (outN + 3) / 4;
    float* hiRow = ws + (size_t)NROWS * HOFF[j] + (size_t)row * HSTR[j];
#pragma unroll
    for (int q0 = 0; q0 < NCH; q0 += 64) {
      int q = q0 + lane;
      if (q < NCH) {
        // taps for outputs n0=4q..4q+3 live at padded idx 8q+4 .. 8q+21 (16B aligned)
        const float* pp = cur + 8 * q + 4;
        float xv[20];
#pragma unroll
        for (int r = 0; r < 5; ++r) {
          float4 v = *reinterpret_cast<const float4*>(pp + 4 * r);
          xv[4 * r] = v.x; xv[4 * r + 1] = v.y; xv[4 * r + 2] = v.z; xv[4 * r + 3] = v.w;
        }
        f2 a0 = {0.f, 0.f}, a1 = {0.f, 0.f}, a2 = {0.f, 0.f}, a3 = {0.f, 0.f};
#pragma unroll
        for (int k = 0; k < 12; ++k) {
          f2 c = (f2){REC_LO[k], REC_HI[k]};
          a0 += xv[k] * c; a1 += xv[2 + k] * c; a2 += xv[4 + k] * c; a3 += xv[6 + k] * c;
        }
        if (j < 7) {
          *reinterpret_cast<f2*>(dst + 14 + 4 * q) = (f2){a0.x, a1.x};
          *reinterpret_cast<f2*>(dst + 16 + 4 * q) = (f2){a2.x, a3.x};
        } else {
          *reinterpret_cast<float4*>(ws + (size_t)NROWS * 1108 + (size_t)row * 16 + 4 * q) =
              make_float4(a0.x, a1.x, a2.x, a3.x);
        }
        *reinterpret_cast<float4*>(hiRow + 4 * q) = make_float4(a0.y, a1.y, a2.y, a3.y);
      }
    }
    if (j < 7) {
      // pads for next level (overwrites chunk-ghost values at 14+outN..)
      if (lane < 10) dst[13 - lane] = dst[14 + lane];
      if (lane < 11) dst[14 + outN + lane] = dst[14 + outN - 1 - lane];
      float* t = cur; cur = dst; dst = t;
    }
  }
}

// ---------------- Fused 8-level synthesis: one WAVE per row, 4-pair chunks ----------------
// out[2m]   = sum_t lo[m+t]*DEC_LO[2t+1] + hi[m+t]*DEC_HI[2t+1]
// out[2m+1] = sum_t lo[m+t]*DEC_LO[2t]   + hi[m+t]*DEC_HI[2t]
__global__ __launch_bounds__(256) void sfb_fused(const float* __restrict__ ws,
                                                 float* __restrict__ out) {
  __shared__ float sP[WPB][272];   // ping: y0,y2,y4,y6 (14,26,74,264) + read slack
  __shared__ float sQ[WPB][524];   // pong: y1,y3,y5,y7 (18,42,138,518) + slack
  __shared__ float sH[WPB][524];   // staged hi
  constexpr int LENSY[8] = {14, 18, 26, 42, 74, 137, 264, 517};
  constexpr int HSOFF[8] = {1124, 1072, 1044, 1000, 924, 784, 520, 0};  // hm, hi6..hi0
  constexpr int HSSTR[8] = {16, 20, 28, 44, 76, 140, 264, 520};
  const int wid = threadIdx.x >> 6;
  const int lane = threadIdx.x & 63;
  const int row = blockIdx.x * WPB + wid;
  float* ping = sP[wid];
  float* pong = sQ[wid];
  float* hbuf = sH[wid];

  if (lane < 4) {  // y0 = loMixed (stride 16; ghost elems 14,15 land in slack)
    float4 v = *reinterpret_cast<const float4*>(ws + (size_t)NROWS * 1140 + (size_t)row * 16 + 4 * lane);
    *reinterpret_cast<float4*>(ping + 4 * lane) = v;
  }

  float* cur = ping;
  float* dst = pong;
#pragma unroll
  for (int s = 0; s < 8; ++s) {
    const int N = LENSY[s];
    const int NH4 = (N + 3) / 4;
    const float* hsrc = ws + (size_t)NROWS * HSOFF[s] + (size_t)row * HSSTR[s];
#pragma unroll
    for (int q0 = 0; q0 < NH4; q0 += 64) {  // stage hi: float4 in, b128 to LDS
      int q = q0 + lane;
      if (q < NH4) {
        float4 v = *reinterpret_cast<const float4*>(hsrc + 4 * q);
        *reinterpret_cast<float4*>(hbuf + 4 * q) = v;
      }
    }
    const int NP = N - 5;
    const int PCH = (NP + 3) / 4;
#pragma unroll
    for (int q0 = 0; q0 < PCH; q0 += 64) {
      int q = q0 + lane;
      if (q < PCH) {
        int m0 = 4 * q;
        float lv[12], hv[12];
#pragma unroll
        for (int r = 0; r < 3; ++r) {
          float4 a = *reinterpret_cast<const float4*>(cur + m0 + 4 * r);
          lv[4 * r] = a.x; lv[4 * r + 1] = a.y; lv[4 * r + 2] = a.z; lv[4 * r + 3] = a.w;
          float4 b = *reinterpret_cast<const float4*>(hbuf + m0 + 4 * r);
          hv[4 * r] = b.x; hv[4 * r + 1] = b.y; hv[4 * r + 2] = b.z; hv[4 * r + 3] = b.w;
        }
        f2 a0 = {0.f, 0.f}, a1 = {0.f, 0.f}, a2 = {0.f, 0.f}, a3 = {0.f, 0.f};
#pragma unroll
        for (int t = 0; t < 6; ++t) {
          f2 dl = (f2){DEC_LO[2 * t + 1], DEC_LO[2 * t]};
          f2 dh = (f2){DEC_HI[2 * t + 1], DEC_HI[2 * t]};
          a0 += lv[t] * dl + hv[t] * dh;
          a1 += lv[1 + t] * dl + hv[1 + t] * dh;
          a2 += lv[2 + t] * dl + hv[2 + t] * dh;
          a3 += lv[3 + t] * dl + hv[3 + t] * dh;
        }
        if (s < 7) {
          *reinterpret_cast<float4*>(dst + 2 * m0)     = make_float4(a0.x, a0.y, a1.x, a1.y);
          *reinterpret_cast<float4*>(dst + 2 * m0 + 4) = make_float4(a2.x, a2.y, a3.x, a3.y);
        } else {
          float* orow = out + (size_t)row * 1024 + 2 * m0;
          *reinterpret_cast<float4*>(orow)     = make_float4(a0.x, a0.y, a1.x, a1.y);
          *reinterpret_cast<float4*>(orow + 4) = make_float4(a2.x, a2.y, a3.x, a3.y);
        }
      }
    }
    if (s < 7) { float* t = cur; cur = dst; dst = t; }
  }
}

// einsum('bix,iox->box') at len 14 (rows padded to stride 16 in ws).
__global__ void mix_kernel(const float* __restrict__ in, const float* __restrict__ w,
                           float* __restrict__ out) {
  __shared__ float s_in[4][896];
  int b0 = blockIdx.x * 4;
  int t = threadIdx.x;  // 896 threads; t -> (o=t/14, x=t%14) and (i=t/14, x=t%14)
  int i = t / 14, xx = t % 14;
#pragma unroll
  for (int bb = 0; bb < 4; ++bb)
    s_in[bb][t] = in[((size_t)(b0 + bb) * 64 + i) * 16 + xx];
  __syncthreads();
  float acc[4] = {0.f, 0.f, 0.f, 0.f};
#pragma unroll 8
  for (int k = 0; k < 64; ++k) {
    float wv = w[k * 896 + t];
#pragma unroll
    for (int bb = 0; bb < 4; ++bb) acc[bb] += s_in[bb][k * 14 + xx] * wv;
  }
#pragma unroll
  for (int bb = 0; bb < 4; ++bb)
    out[((size_t)(b0 + bb) * 64 + i) * 16 + xx] = acc[bb];
}

extern "C" void kernel_launch(void* const* d_in, const int* in_sizes, int n_in,
                              void* d_out, int out_size, void* d_ws, size_t ws_size,
                              hipStream_t stream) {
  (void)in_sizes; (void)n_in; (void)out_size; (void)ws_size;
  const float* x  = (const float*)d_in[0];
  const float* w1 = (const float*)d_in[1];
  const float* w2 = (const float*)d_in[2];
  float* out = (float*)d_out;
  float* ws  = (float*)d_ws;

  afb_fused<<<NROWS / WPB, 64 * WPB, 0, stream>>>(x, ws);

  float* loFinal = ws + (size_t)NROWS * 1108;
  float* hm      = ws + (size_t)NROWS * 1124;
  float* loMixed = ws + (size_t)NROWS * 1140;
  float* hi7     = ws + (size_t)NROWS * 1092;
  mix_kernel<<<64, 896, 0, stream>>>(loFinal, w1, loMixed);
  mix_kernel<<<64, 896, 0, stream>>>(hi7, w2, hm);

  sfb_fused<<<NROWS / WPB, 64 * WPB, 0, stream>>>(ws, out);
}